// Round 1
// baseline (137.558 us; speedup 1.0000x reference)
//
#include <hip/hip_runtime.h>
#include <stdint.h>

#define BB 8
#define C  64
#define H  256
#define W  256
#define HW (H*W)
#define EPSV 1e-6f

// ---------------- K1: per-(b,c) stats of (x + b_move) ----------------
__global__ __launch_bounds__(512) void k_stats(const float* __restrict__ x,
                                               const float* __restrict__ bmove,
                                               float* __restrict__ sums /* [3][512] */) {
  int bc = blockIdx.x;            // b*64 + c
  int c  = bc & 63;
  float bm = bmove[c];
  const float4* p = (const float4*)(x + (size_t)bc * HW);
  float s = 0.f, s2 = 0.f, sa = 0.f;
  for (int it = threadIdx.x; it < HW / 4; it += 512) {
    float4 v = p[it];
    float a0 = v.x + bm, a1 = v.y + bm, a2 = v.z + bm, a3 = v.w + bm;
    s  += a0 + a1 + a2 + a3;
    s2 += a0*a0 + a1*a1 + a2*a2 + a3*a3;
    sa += fabsf(a0) + fabsf(a1) + fabsf(a2) + fabsf(a3);
  }
  // wave reduce (64 lanes)
  for (int off = 32; off > 0; off >>= 1) {
    s  += __shfl_down(s,  off, 64);
    s2 += __shfl_down(s2, off, 64);
    sa += __shfl_down(sa, off, 64);
  }
  __shared__ float red[8][3];
  int wid = threadIdx.x >> 6, lane = threadIdx.x & 63;
  if (lane == 0) { red[wid][0] = s; red[wid][1] = s2; red[wid][2] = sa; }
  __syncthreads();
  if (threadIdx.x == 0) {
    float S = 0.f, S2 = 0.f, SA = 0.f;
    for (int i = 0; i < 8; i++) { S += red[i][0]; S2 += red[i][1]; SA += red[i][2]; }
    sums[bc] = S; sums[512 + bc] = S2; sums[1024 + bc] = SA;
  }
}

// ---------------- K2: gate (conv1d over C + sigmoid), weight signs/scales ----
__global__ __launch_bounds__(512) void k_gate(const float* __restrict__ sums,
                                              const float* __restrict__ w_conv,
                                              const float* __restrict__ w1d,
                                              float* __restrict__ alpha,
                                              unsigned long long* __restrict__ wsign) {
  __shared__ float stA[512], stM[512], stS[512];  // [b*64 + c]
  __shared__ float swv[64];
  int tid = threadIdx.x;
  {
    float s = sums[tid], s2 = sums[512 + tid], sa = sums[1024 + tid];
    const float invN = 1.f / (float)HW;
    float mean = s * invN;
    float var  = (s2 - s * s * invN) * (1.f / (float)(HW - 1)) + EPSV;
    stA[tid] = sa * invN;
    stM[tid] = mean;
    stS[tid] = sqrtf(var);
  }
  if (tid < 64) {
    int o = tid;
    const float* wo = w_conv + o * 576;   // [i][kh][kw] = i*9 + tap
    float s = 0.f;
    unsigned long long wb[9] = {0,0,0,0,0,0,0,0,0};
    for (int i = 0; i < 64; i++) {
      #pragma unroll
      for (int t = 0; t < 9; t++) {
        float v = wo[i * 9 + t];
        s += fabsf(v);
        if (v > 0.f) wb[t] |= (1ull << i);
      }
    }
    swv[o] = s * (1.f / 576.f);
    #pragma unroll
    for (int t = 0; t < 9; t++) wsign[o * 9 + t] = wb[t];
  }
  __syncthreads();
  int b = tid >> 6, c = tid & 63;
  float y = 0.f;
  #pragma unroll
  for (int k = 0; k < 3; k++) {
    int cc = c + k - 1;
    if (cc >= 0 && cc < 64) {
      int j = b * 64 + cc;
      y += stA[j] * w1d[0 * 3 + k] + stM[j] * w1d[1 * 3 + k] + stS[j] * w1d[2 * 3 + k];
    }
  }
  float gate = 1.f / (1.f + expf(-y));
  alpha[tid] = gate * swv[c];   // folds scale_w[o] * gate[b][o]
}

// ---------------- K3: pack signs of (x + b_move) into u64[B][H][W] ----------
__global__ __launch_bounds__(256) void k_pack(const float* __restrict__ x,
                                              const float* __restrict__ bmove,
                                              unsigned long long* __restrict__ packed) {
  int blk = blockIdx.x;                       // 512 blocks
  int b  = blk >> 6;
  int h  = ((blk & 63) << 2) + (threadIdx.x >> 6);
  int w0 = (threadIdx.x & 63) << 2;
  const float* px = x + (size_t)b * C * HW + h * W + w0;
  unsigned long long wd0 = 0, wd1 = 0, wd2 = 0, wd3 = 0;
  #pragma unroll 8
  for (int c = 0; c < 64; c++) {
    float4 v = *(const float4*)(px + (size_t)c * HW);
    float bm = bmove[c];
    unsigned long long bit = 1ull << c;
    if (v.x + bm > 0.f) wd0 |= bit;
    if (v.y + bm > 0.f) wd1 |= bit;
    if (v.z + bm > 0.f) wd2 |= bit;
    if (v.w + bm > 0.f) wd3 |= bit;
  }
  unsigned long long* dst = packed + (size_t)(b * H + h) * W + w0;
  dst[0] = wd0; dst[1] = wd1; dst[2] = wd2; dst[3] = wd3;
}

// ---------------- K4: XNOR conv + scale + rprelu + residual ----------------
__global__ __launch_bounds__(256) void k_conv(const unsigned long long* __restrict__ packed,
                                              const unsigned long long* __restrict__ wsign,
                                              const float* __restrict__ alpha,
                                              const float* __restrict__ x,
                                              const float* __restrict__ pr_b0,
                                              const float* __restrict__ prelu_a,
                                              const float* __restrict__ pr_b1,
                                              float* __restrict__ out) {
  int bh = blockIdx.x;            // b*256 + h
  int b = bh >> 8, h = bh & 255;
  int w = threadIdx.x;
  __shared__ unsigned long long rows[3][W];
  bool r0v = (h > 0), r2v = (h < H - 1);
  const unsigned long long* pb = packed + (size_t)b * HW;
  rows[1][w] = pb[h * W + w];
  if (r0v) rows[0][w] = pb[(h - 1) * W + w];
  if (r2v) rows[2][w] = pb[(h + 1) * W + w];
  __syncthreads();

  bool lv = (w > 0), rv = (w < W - 1);
  unsigned long long vmL = lv ? ~0ull : 0ull;
  unsigned long long vmR = rv ? ~0ull : 0ull;
  unsigned long long nL[3], nC[3], nR[3];
  #pragma unroll
  for (int r = 0; r < 3; r++) {
    nC[r] = rows[r][w];
    nL[r] = rows[r][lv ? w - 1 : w];
    nR[r] = rows[r][rv ? w + 1 : w];
  }
  int nrows = 1 + (int)r0v + (int)r2v;
  int ncols = 1 + (int)lv + (int)rv;
  float base = 64.f * (float)(nrows * ncols);
  size_t xoff = (size_t)b * C * HW + h * W + w;

  for (int o = 0; o < 64; o++) {
    const unsigned long long* wso = wsign + o * 9;
    int cnt = 0;
    if (r0v) {
      cnt += __popcll((nL[0] ^ wso[0]) & vmL);
      cnt += __popcll( nC[0] ^ wso[1]);
      cnt += __popcll((nR[0] ^ wso[2]) & vmR);
    }
    cnt += __popcll((nL[1] ^ wso[3]) & vmL);
    cnt += __popcll( nC[1] ^ wso[4]);
    cnt += __popcll((nR[1] ^ wso[5]) & vmR);
    if (r2v) {
      cnt += __popcll((nL[2] ^ wso[6]) & vmL);
      cnt += __popcll( nC[2] ^ wso[7]);
      cnt += __popcll((nR[2] ^ wso[8]) & vmR);
    }
    float dot = base - 2.f * (float)cnt;
    float v = dot * alpha[b * 64 + o];
    float y = v + pr_b0[o];
    y = (y > 0.f) ? y : prelu_a[o] * y;
    y += pr_b1[o];
    size_t idx = xoff + (size_t)o * HW;
    out[idx] = y + x[idx];
  }
}

extern "C" void kernel_launch(void* const* d_in, const int* in_sizes, int n_in,
                              void* d_out, int out_size, void* d_ws, size_t ws_size,
                              hipStream_t stream) {
  const float* x       = (const float*)d_in[0];
  const float* b_move  = (const float*)d_in[1];
  const float* w_conv  = (const float*)d_in[2];
  const float* w1d     = (const float*)d_in[3];
  const float* pr_b0   = (const float*)d_in[4];
  const float* prelu_a = (const float*)d_in[5];
  const float* pr_b1   = (const float*)d_in[6];
  float* out = (float*)d_out;

  char* ws = (char*)d_ws;
  // ws layout: packed u64[8*256*256] = 4 MiB, then sums (3*512 f32),
  // alpha (512 f32), wsign (64*9 u64)
  unsigned long long* packed = (unsigned long long*)ws;
  float* sums  = (float*)(ws + 4194304);
  float* alpha = (float*)(ws + 4194304 + 6144);
  unsigned long long* wsign = (unsigned long long*)(ws + 4194304 + 6144 + 2048);

  k_stats<<<512, 512, 0, stream>>>(x, b_move, sums);
  k_pack<<<512, 256, 0, stream>>>(x, b_move, packed);
  k_gate<<<1, 512, 0, stream>>>(sums, w_conv, w1d, alpha, wsign);
  k_conv<<<BB * H, 256, 0, stream>>>(packed, wsign, alpha, x,
                                     pr_b0, prelu_a, pr_b1, out);
}